// Round 8
// baseline (462.889 us; speedup 1.0000x reference)
//
#include <hip/hip_runtime.h>
#include <cstdint>
#include <cstddef>

// Inputs/outputs FP32 (per reference); internal tensors bf16 (+ V/P in f16).
// Sizes: B=2, N=2048, C=1024, R=64, H=16, Dh=64.

typedef short short8 __attribute__((ext_vector_type(8)));
typedef float f32x4 __attribute__((ext_vector_type(4)));
typedef __fp16 half2v __attribute__((ext_vector_type(2)));
typedef __fp16 half4 __attribute__((ext_vector_type(4)));

#define MFMA16(a, b, c) __builtin_amdgcn_mfma_f32_16x16x32_bf16((a), (b), (c), 0, 0, 0)
#define MFMA16F(a, b, c) __builtin_amdgcn_mfma_f32_16x16x16f16((a), (b), (c), 0, 0, 0)

// Q pre-scale: Dh^-0.5 (=0.125) * log2(e) -> softmax in exp2 domain.
#define QSCALE 0.18033688011112042f

__device__ __forceinline__ float fexp2(float x) { return __builtin_amdgcn_exp2f(x); }

// fast bf16 round (round-half-up)
__device__ __forceinline__ uint16_t f2b(float f) {
    return (uint16_t)((__float_as_uint(f) + 0x8000u) >> 16);
}
// pack two floats -> two bf16 in one u32 (lo = a, hi = b)
__device__ __forceinline__ uint32_t pkbf(float a, float b) {
    uint32_t ua = __float_as_uint(a) + 0x8000u;
    uint32_t ub = __float_as_uint(b) + 0x8000u;
    return __builtin_amdgcn_perm(ub, ua, 0x07060302);
}
// f32 -> f16 bits (rtz)
__device__ __forceinline__ uint16_t f2h(float f) {
    half2v t = __builtin_amdgcn_cvt_pkrtz(f, f);
    return __builtin_bit_cast(uint16_t, t[0]);
}
__device__ __forceinline__ float gelu_exact(float x) {
    return 0.5f * x * (1.0f + erff(x * 0.70710678118654752440f));
}
__device__ __forceinline__ short8 ld8(const uint16_t* p) {
    return *reinterpret_cast<const short8*>(p);
}

// ---------------------------------------------------------------------------
// prep: convert x fp32->bf16 + transpose/convert all 4 weights.
// grid 3584 x 256: blocks [0,2048) = x, [2048,3584) = weights.
// ---------------------------------------------------------------------------
__global__ __launch_bounds__(256) void prep(const float* __restrict__ x,
                                            const float* __restrict__ wqa,
                                            const float* __restrict__ wqb,
                                            const float* __restrict__ wpa,
                                            const float* __restrict__ wpb,
                                            uint16_t* __restrict__ xb,
                                            uint16_t* __restrict__ wqaT,
                                            uint16_t* __restrict__ wqbT,
                                            uint16_t* __restrict__ wpaT,
                                            uint16_t* __restrict__ wpbT) {
    const int bid = blockIdx.x;
    if (bid < 2048) {
        size_t i = ((size_t)bid * 256 + threadIdx.x) * 8;
        f32x4 a0 = *reinterpret_cast<const f32x4*>(x + i);
        f32x4 a1 = *reinterpret_cast<const f32x4*>(x + i + 4);
        uint32_t* o = reinterpret_cast<uint32_t*>(xb + i);
        o[0] = pkbf(a0[0], a0[1]);
        o[1] = pkbf(a0[2], a0[3]);
        o[2] = pkbf(a1[0], a1[1]);
        o[3] = pkbf(a1[2], a1[3]);
        return;
    }
    int i = (bid - 2048) * 256 + threadIdx.x;
    if (i < 65536) {
        int r = i >> 6, c = i & 63;
        wqaT[(size_t)c * 1024 + r] = f2b(wqa[i]);
    } else if (i < 262144) {
        int j = i - 65536;
        int r = j / 3072, c = j - r * 3072;
        wqbT[(size_t)c * 64 + r] = f2b(wqb[j]);
    } else if (i < 327680) {
        int j = i - 262144;
        int r = j >> 6, c = j & 63;
        wpaT[(size_t)c * 1024 + r] = f2b(wpa[j]);
    } else {
        int j = i - 327680;
        int r = j >> 10, c = j & 1023;
        wpbT[(size_t)c * 64 + r] = f2b(wpb[j]);
    }
}

// ---------------------------------------------------------------------------
// rank_gemm: out[4096][64] = gelu( X[4096][1024] @ W[1024][64] )
// 512 threads = 8 waves: cc = w&3 (16-col chunk), kh = w>>2 (K half);
// split-K partials combined via LDS. grid 256 x 512.
// ---------------------------------------------------------------------------
__global__ __launch_bounds__(512) void rank_gemm(const uint16_t* __restrict__ X,
                                                 const uint16_t* __restrict__ WT,
                                                 uint16_t* __restrict__ out) {
    __shared__ float ps[4][16][17];
    const int tid = threadIdx.x;
    const int wave = tid >> 6, lane = tid & 63;
    const int l16 = lane & 15, quad = lane >> 4;
    const int cc = wave & 3, kh = wave >> 2;
    const int rowg = blockIdx.x;

    const uint16_t* ap = X + (size_t)(rowg * 16 + l16) * 1024 + kh * 512 + quad * 8;
    const uint16_t* bp = WT + (size_t)(cc * 16 + l16) * 1024 + kh * 512 + quad * 8;

    f32x4 acc = {0.f, 0.f, 0.f, 0.f};
#pragma unroll 8
    for (int k = 0; k < 16; ++k) {
        acc = MFMA16(ld8(ap + k * 32), ld8(bp + k * 32), acc);
    }

    if (kh == 1) {
#pragma unroll
        for (int r = 0; r < 4; ++r) ps[cc][quad * 4 + r][l16] = acc[r];
    }
    __syncthreads();
    if (kh == 0) {
        const int col = cc * 16 + l16;
#pragma unroll
        for (int r = 0; r < 4; ++r) {
            int row = rowg * 16 + quad * 4 + r;
            float v = acc[r] + ps[cc][quad * 4 + r][l16];
            out[(size_t)row * 64 + col] = f2b(gelu_exact(v));
        }
    }
}

// ---------------------------------------------------------------------------
// expand_qkv: qkv = H1[4096][64] @ Wb[64][3072].
//   Q/K waves: LDS-transpose epilogue -> n-major Qb/Kb (bf16), coalesced.
//   V waves: OPERAND-SWAPPED MFMA (A=W^T-frag, B=H1^T-frag) -> D = V^T tile
//            directly; store planar Vtb[bh][d][n] (f16). vtrans eliminated.
// grid 3072 x 256.
// ---------------------------------------------------------------------------
__global__ __launch_bounds__(256) void expand_qkv(const uint16_t* __restrict__ H1,
                                                  const uint16_t* __restrict__ WT,
                                                  uint16_t* __restrict__ Qb,
                                                  uint16_t* __restrict__ Kb,
                                                  uint16_t* __restrict__ Vtb) {
    __shared__ __align__(16) uint16_t po[4][16 * 72];
    const int wave = threadIdx.x >> 6;
    const int lane = threadIdx.x & 63;
    const int l16 = lane & 15, quad = lane >> 4;
    const int wg = blockIdx.x * 4 + wave;       // 0..12287
    const int rowg = wg / 48;                   // 0..255
    const int colg = wg % 48;                   // 0..47

    const uint16_t* ap = H1 + (size_t)(rowg * 16 + l16) * 64 + quad * 8;
    const uint16_t* bp = WT + ((size_t)colg * 64 + l16) * 64 + quad * 8;

    const int which = colg >> 4;   // 0=q 1=k 2=v  (wave-uniform)
    const int h = colg & 15;

    f32x4 acc[4];
#pragma unroll
    for (int c = 0; c < 4; ++c) acc[c] = (f32x4){0.f, 0.f, 0.f, 0.f};

    if (which < 2) {
#pragma unroll
        for (int i = 0; i < 2; ++i) {
            short8 a = ld8(ap + i * 32);
#pragma unroll
            for (int c = 0; c < 4; ++c) {
                acc[c] = MFMA16(a, ld8(bp + (size_t)c * 1024 + i * 32), acc[c]);
            }
        }
        uint16_t* pw = po[wave];
#pragma unroll
        for (int c = 0; c < 4; ++c) {
#pragma unroll
            for (int r = 0; r < 4; ++r) {
                float v = acc[c][r];
                uint16_t u = (which == 0) ? f2b(v * QSCALE) : f2b(v);
                pw[(quad * 4 + r) * 72 + c * 16 + l16] = u;
            }
        }
        __builtin_amdgcn_s_waitcnt(0);  // wave-local LDS round trip

        const int grow = rowg * 16 + l16;
        const int b = grow >> 11, n = grow & 2047;
        uint16_t* base = (which == 0) ? Qb : Kb;
        uint16_t* dst = base + ((size_t)(b * 16 + h) * 2048 + n) * 64 + quad * 16;
        *reinterpret_cast<short8*>(dst) = ld8(&pw[l16 * 72 + quad * 16]);
        *reinterpret_cast<short8*>(dst + 8) = ld8(&pw[l16 * 72 + quad * 16 + 8]);
    } else {
        // V^T = W_v^T (64d x 64k) . H1^T (64k x 16n): swap MFMA operands.
#pragma unroll
        for (int i = 0; i < 2; ++i) {
            short8 a = ld8(ap + i * 32);
#pragma unroll
            for (int c = 0; c < 4; ++c) {
                acc[c] = MFMA16(ld8(bp + (size_t)c * 1024 + i * 32), a, acc[c]);
            }
        }
        // C-layout: row = d = c*16 + quad*4 + r, col = n = rowg*16 + l16
        const int grow = rowg * 16 + l16;
        const int b = grow >> 11, n = grow & 2047;
        uint16_t* vb = Vtb + (size_t)(b * 16 + h) * 64 * 2048 + n;
#pragma unroll
        for (int c = 0; c < 4; ++c) {
#pragma unroll
            for (int r = 0; r < 4; ++r) {
                int d = c * 16 + quad * 4 + r;
                vb[(size_t)d * 2048] = f2h(acc[c][r]);
            }
            vb += 0;  // d advances via c in the index above
        }
    }
}

// ---------------------------------------------------------------------------
// Flash attention v4: ZERO-LDS main loop. Both MFMA A-operands stream
// directly from global (L2/L3-resident):
//   S^T: A = Kb rows (n-major, b128/lane)  B = Q-frag (registers)
//   PV:  A = Vtb rows (d-major, b64/lane)  B = P^T packed f16 (registers)
// No barriers, no staging, no bank conflicts. No-max softmax (exp2 domain).
// Small per-wave LDS only for the coalescing epilogue transpose.
// grid = bh(32)*qg(32) = 1024 x 256; wave = 16 q-rows.
// ---------------------------------------------------------------------------
__global__ __launch_bounds__(256) void attn_kernel(const uint16_t* __restrict__ Qb,
                                                   const uint16_t* __restrict__ Kb,
                                                   const uint16_t* __restrict__ Vtb,
                                                   uint16_t* __restrict__ AO) {
    __shared__ __align__(16) uint16_t pws[4][16 * 72];

    const int tid = threadIdx.x;
    const int wave = tid >> 6;
    const int lane = tid & 63;
    const int l16 = lane & 15, quad = lane >> 4;
    const int bh = blockIdx.x >> 5;
    const int qg = blockIdx.x & 31;
    const int q16 = qg * 64 + wave * 16;

    const uint16_t* qp = Qb + ((size_t)(bh * 2048 + q16 + l16)) * 64 + quad * 8;
    const short8 qf0 = ld8(qp);
    const short8 qf1 = ld8(qp + 32);

    const uint16_t* kbase = Kb + (size_t)bh * 2048 * 64 + (size_t)l16 * 64 + quad * 8;
    const uint16_t* vbase = Vtb + (size_t)bh * 64 * 2048 + (size_t)l16 * 2048 + quad * 4;

    f32x4 ot[4];
#pragma unroll
    for (int dc = 0; dc < 4; ++dc) ot[dc] = (f32x4){0.f, 0.f, 0.f, 0.f};
    float lp = 0.f;

    for (int t = 0; t < 32; ++t) {
        // S^T per 16-key chunk; P^T packed straight into f16 B-fragments
        half4 pb[4];
#pragma unroll
        for (int kc = 0; kc < 4; ++kc) {
            const uint16_t* kp = kbase + (size_t)(t * 64 + kc * 16) * 64;
            f32x4 st = {0.f, 0.f, 0.f, 0.f};
            st = MFMA16(ld8(kp), qf0, st);
            st = MFMA16(ld8(kp + 32), qf1, st);
            float p0 = fexp2(st[0]), p1 = fexp2(st[1]);
            float p2 = fexp2(st[2]), p3 = fexp2(st[3]);
            lp += (p0 + p1) + (p2 + p3);
            half2v lo = __builtin_amdgcn_cvt_pkrtz(p0, p1);
            half2v hi = __builtin_amdgcn_cvt_pkrtz(p2, p3);
            pb[kc] = __builtin_shufflevector(lo, hi, 0, 1, 2, 3);
        }

        // O^T += V^T . P^T  (A direct from global d-major V^T)
#pragma unroll
        for (int dc = 0; dc < 4; ++dc) {
            const uint16_t* vp = vbase + (size_t)dc * 16 * 2048 + t * 64;
#pragma unroll
            for (int kc = 0; kc < 4; ++kc) {
                const half4 av = *reinterpret_cast<const half4*>(vp + kc * 16);
                ot[dc] = MFMA16F(av, pb[kc], ot[dc]);
            }
        }
    }

    // epilogue: l reduce across quads (same q column), O^T -> O via LDS
    lp += __shfl_xor(lp, 16, 64);
    lp += __shfl_xor(lp, 32, 64);
    const float inv = 1.0f / lp;

    uint16_t* pw = pws[wave];
#pragma unroll
    for (int dc = 0; dc < 4; ++dc) {
        uint32_t* w = reinterpret_cast<uint32_t*>(&pw[l16 * 72 + dc * 16 + quad * 4]);
        w[0] = pkbf(ot[dc][0] * inv, ot[dc][1] * inv);
        w[1] = pkbf(ot[dc][2] * inv, ot[dc][3] * inv);
    }
    __builtin_amdgcn_s_waitcnt(0);      // wave-local round trip

    const int b = bh >> 4, h = bh & 15;
    const int grow = b * 2048 + q16 + l16;
    uint16_t* dst = AO + (size_t)grow * 1024 + h * 64 + quad * 16;
    *reinterpret_cast<short8*>(dst) = ld8(&pw[l16 * 72 + quad * 16]);
    *reinterpret_cast<short8*>(dst + 8) = ld8(&pw[l16 * 72 + quad * 16 + 8]);
}

// ---------------------------------------------------------------------------
// proj_fused: out_f32[4096][1024] =
//   gelu( AO[4096][1024] @ wpa[1024][64] + bpa ) @ wpb[64][1024] + bpb
// Stage 1: split-K rank GEMM -> h2 tile (16x64) in LDS (bf16, gelu applied).
// Stage 2: 8 waves x 8 col-chunks of the 16x1024 output. grid 256 x 512.
// ---------------------------------------------------------------------------
__global__ __launch_bounds__(512) void proj_fused(const uint16_t* __restrict__ AO,
                                                  const uint16_t* __restrict__ wpaT,
                                                  const float* __restrict__ bpa,
                                                  const uint16_t* __restrict__ wpbT,
                                                  const float* __restrict__ bpb,
                                                  float* __restrict__ out) {
    __shared__ float ps[4][16][17];
    __shared__ __align__(16) uint16_t h2L[16 * 72];
    const int tid = threadIdx.x;
    const int wave = tid >> 6, lane = tid & 63;
    const int l16 = lane & 15, quad = lane >> 4;
    const int cc = wave & 3, kh = wave >> 2;
    const int rowg = blockIdx.x;

    // ---- stage 1: h2 = gelu(AO @ wpa + bpa), split-K over 8 waves ----
    {
        const uint16_t* ap = AO + (size_t)(rowg * 16 + l16) * 1024 + kh * 512 + quad * 8;
        const uint16_t* bp = wpaT + (size_t)(cc * 16 + l16) * 1024 + kh * 512 + quad * 8;
        f32x4 acc = {0.f, 0.f, 0.f, 0.f};
#pragma unroll 8
        for (int k = 0; k < 16; ++k) {
            acc = MFMA16(ld8(ap + k * 32), ld8(bp + k * 32), acc);
        }
        if (kh == 1) {
#pragma unroll
            for (int r = 0; r < 4; ++r) ps[cc][quad * 4 + r][l16] = acc[r];
        }
        __syncthreads();
        if (kh == 0) {
            const int col = cc * 16 + l16;
            const float bv = bpa[col];
#pragma unroll
            for (int r = 0; r < 4; ++r) {
                float v = acc[r] + ps[cc][quad * 4 + r][l16] + bv;
                h2L[(quad * 4 + r) * 72 + col] = f2b(gelu_exact(v));
            }
        }
        __syncthreads();
    }

    // ---- stage 2: out = h2 @ wpb + bpb ----
    const short8 a0 = ld8(&h2L[l16 * 72 + quad * 8]);
    const short8 a1 = ld8(&h2L[l16 * 72 + 32 + quad * 8]);
#pragma unroll
    for (int i = 0; i < 8; ++i) {
        const int col0 = (wave * 8 + i) * 16;
        const uint16_t* bp = wpbT + (size_t)(col0 + l16) * 64 + quad * 8;
        f32x4 acc = {0.f, 0.f, 0.f, 0.f};
        acc = MFMA16(a0, ld8(bp), acc);
        acc = MFMA16(a1, ld8(bp + 32), acc);
        const float bv = bpb[col0 + l16];
#pragma unroll
        for (int r = 0; r < 4; ++r) {
            int row = rowg * 16 + quad * 4 + r;
            out[(size_t)row * 1024 + col0 + l16] = acc[r] + bv;
        }
    }
}

// ---------------------------------------------------------------------------
extern "C" void kernel_launch(void* const* d_in, const int* in_sizes, int n_in,
                              void* d_out, int out_size, void* d_ws, size_t ws_size,
                              hipStream_t stream) {
    const float* x   = (const float*)d_in[0];   // [2,2048,1024]
    const float* wqa = (const float*)d_in[1];   // [1024,64]
    const float* wqb = (const float*)d_in[2];   // [64,3072]
    const float* wpa = (const float*)d_in[3];   // [1024,64]
    const float* bpa = (const float*)d_in[4];   // [64]
    const float* wpb = (const float*)d_in[5];   // [64,1024]
    const float* bpb = (const float*)d_in[6];   // [1024]
    float* out = (float*)d_out;                 // [2,2048,1024]
    uint16_t* ws = (uint16_t*)d_ws;

    // workspace layout (u16 element offsets; all 16B-aligned)
    uint16_t* wqaT = ws + 0;         //  64x1024
    uint16_t* wqbT = ws + 65536;     // 3072x64
    uint16_t* wpaT = ws + 262144;    //  64x1024
    uint16_t* wpbT = ws + 327680;    // 1024x64
    uint16_t* h1   = ws + 393216;    // 4096x64
    uint16_t* Qb   = ws + 655360;    // [32][2048][64] bf16
    uint16_t* Kb   = ws + 4849664;   // [32][2048][64] bf16
    uint16_t* xb   = Kb;             // x bf16 — dead before Kb written
    uint16_t* Vtb  = ws + 9043968;   // [32][64][2048] f16
    uint16_t* AO   = ws + 13238272;  // 4096x1024 bf16
    (void)in_sizes; (void)n_in; (void)out_size; (void)ws_size;

    prep<<<3584, 256, 0, stream>>>(x, wqa, wqb, wpa, wpb, xb, wqaT, wqbT, wpaT, wpbT);
    rank_gemm<<<256, 512, 0, stream>>>(xb, wqaT, h1);
    expand_qkv<<<3072, 256, 0, stream>>>(h1, wqbT, Qb, Kb, Vtb);
    attn_kernel<<<1024, 256, 0, stream>>>(Qb, Kb, Vtb, AO);
    proj_fused<<<256, 512, 0, stream>>>(AO, wpaT, bpa, wpbT, bpb, out);
}

// Round 10
// 172.039 us; speedup vs baseline: 2.6906x; 2.6906x over previous
//
#include <hip/hip_runtime.h>
#include <cstdint>
#include <cstddef>

// Inputs/outputs FP32 (per reference); internal tensors bf16 (+ V/P in f16).
// Sizes: B=2, N=2048, C=1024, R=64, H=16, Dh=64.

typedef short short8 __attribute__((ext_vector_type(8)));
typedef float f32x4 __attribute__((ext_vector_type(4)));
typedef __fp16 half2v __attribute__((ext_vector_type(2)));
typedef __fp16 half4 __attribute__((ext_vector_type(4)));

#define MFMA16(a, b, c) __builtin_amdgcn_mfma_f32_16x16x32_bf16((a), (b), (c), 0, 0, 0)
#define MFMA16F(a, b, c) __builtin_amdgcn_mfma_f32_16x16x16f16((a), (b), (c), 0, 0, 0)

// Q pre-scale: Dh^-0.5 (=0.125) * log2(e) -> softmax in exp2 domain.
#define QSCALE 0.18033688011112042f

__device__ __forceinline__ float fexp2(float x) { return __builtin_amdgcn_exp2f(x); }

__device__ __forceinline__ uint16_t f2b(float f) {
    return (uint16_t)((__float_as_uint(f) + 0x8000u) >> 16);
}
__device__ __forceinline__ uint32_t pkbf(float a, float b) {
    uint32_t ua = __float_as_uint(a) + 0x8000u;
    uint32_t ub = __float_as_uint(b) + 0x8000u;
    return __builtin_amdgcn_perm(ub, ua, 0x07060302);
}
__device__ __forceinline__ uint16_t f2h(float f) {
    half2v t = __builtin_amdgcn_cvt_pkrtz(f, f);
    return __builtin_bit_cast(uint16_t, t[0]);
}
__device__ __forceinline__ float gelu_exact(float x) {
    return 0.5f * x * (1.0f + erff(x * 0.70710678118654752440f));
}
__device__ __forceinline__ short8 ld8(const uint16_t* p) {
    return *reinterpret_cast<const short8*>(p);
}

// ---------------------------------------------------------------------------
// prep: convert x fp32->bf16 + transpose/convert all 4 weights.
// ---------------------------------------------------------------------------
__global__ __launch_bounds__(256) void prep(const float* __restrict__ x,
                                            const float* __restrict__ wqa,
                                            const float* __restrict__ wqb,
                                            const float* __restrict__ wpa,
                                            const float* __restrict__ wpb,
                                            uint16_t* __restrict__ xb,
                                            uint16_t* __restrict__ wqaT,
                                            uint16_t* __restrict__ wqbT,
                                            uint16_t* __restrict__ wpaT,
                                            uint16_t* __restrict__ wpbT) {
    const int bid = blockIdx.x;
    if (bid < 2048) {
        size_t i = ((size_t)bid * 256 + threadIdx.x) * 8;
        f32x4 a0 = *reinterpret_cast<const f32x4*>(x + i);
        f32x4 a1 = *reinterpret_cast<const f32x4*>(x + i + 4);
        uint32_t* o = reinterpret_cast<uint32_t*>(xb + i);
        o[0] = pkbf(a0[0], a0[1]);
        o[1] = pkbf(a0[2], a0[3]);
        o[2] = pkbf(a1[0], a1[1]);
        o[3] = pkbf(a1[2], a1[3]);
        return;
    }
    int i = (bid - 2048) * 256 + threadIdx.x;
    if (i < 65536) {
        int r = i >> 6, c = i & 63;
        wqaT[(size_t)c * 1024 + r] = f2b(wqa[i]);
    } else if (i < 262144) {
        int j = i - 65536;
        int r = j / 3072, c = j - r * 3072;
        wqbT[(size_t)c * 64 + r] = f2b(wqb[j]);
    } else if (i < 327680) {
        int j = i - 262144;
        int r = j >> 6, c = j & 63;
        wpaT[(size_t)c * 1024 + r] = f2b(wpa[j]);
    } else {
        int j = i - 327680;
        int r = j >> 10, c = j & 1023;
        wpbT[(size_t)c * 64 + r] = f2b(wpb[j]);
    }
}

// ---------------------------------------------------------------------------
// rank_gemm: out[4096][64] = gelu( X[4096][1024] @ W[1024][64] )
// 512 threads, split-K over 2 wave-groups, partials via LDS. grid 256.
// ---------------------------------------------------------------------------
__global__ __launch_bounds__(512) void rank_gemm(const uint16_t* __restrict__ X,
                                                 const uint16_t* __restrict__ WT,
                                                 uint16_t* __restrict__ out) {
    __shared__ float ps[4][16][17];
    const int tid = threadIdx.x;
    const int wave = tid >> 6, lane = tid & 63;
    const int l16 = lane & 15, quad = lane >> 4;
    const int cc = wave & 3, kh = wave >> 2;
    const int rowg = blockIdx.x;

    const uint16_t* ap = X + (size_t)(rowg * 16 + l16) * 1024 + kh * 512 + quad * 8;
    const uint16_t* bp = WT + (size_t)(cc * 16 + l16) * 1024 + kh * 512 + quad * 8;

    f32x4 acc = {0.f, 0.f, 0.f, 0.f};
#pragma unroll 8
    for (int k = 0; k < 16; ++k) {
        acc = MFMA16(ld8(ap + k * 32), ld8(bp + k * 32), acc);
    }

    if (kh == 1) {
#pragma unroll
        for (int r = 0; r < 4; ++r) ps[cc][quad * 4 + r][l16] = acc[r];
    }
    __syncthreads();
    if (kh == 0) {
        const int col = cc * 16 + l16;
#pragma unroll
        for (int r = 0; r < 4; ++r) {
            int row = rowg * 16 + quad * 4 + r;
            float v = acc[r] + ps[cc][quad * 4 + r][l16];
            out[(size_t)row * 64 + col] = f2b(gelu_exact(v));
        }
    }
}

// ---------------------------------------------------------------------------
// expand_qkv: qkv = H1[4096][64] @ Wb[64][3072].
// Block = 4 waves, all on one colg (one (which,head)); covers a 64-row n-chunk.
//   Q -> Qb[bh][n][d] bf16 (scaled)
//   K -> Kf[bh][t=n/64][4096] bf16, fragment order:
//        idx(key,d) = (key>>4)*1024 + (d>>5)*512 + ((d>>3)&3)*128 + (key&15)*8 + (d&7)
//   V -> Vf[bh][t][4096] f16, paired-kc fragment order:
//        idx(d,key) = (d>>4)*1024 + (key>>5)*512 + ((key>>2)&3)*128 + (d&15)*8
//                     + ((key>>4)&1)*4 + (key&3)
// Each K/V thread stores TWO short8s (tile = 4096 elems = 256 thr x 16).
// grid 3072 (= 64 rowblk x 48 colg) x 256.
// ---------------------------------------------------------------------------
__global__ __launch_bounds__(256) void expand_qkv(const uint16_t* __restrict__ H1,
                                                  const uint16_t* __restrict__ WT,
                                                  uint16_t* __restrict__ Qb,
                                                  uint16_t* __restrict__ Kf,
                                                  uint16_t* __restrict__ Vf) {
    __shared__ __align__(16) uint16_t tl[64 * 72];
    const int tid = threadIdx.x;
    const int wave = tid >> 6;
    const int lane = tid & 63;
    const int l16 = lane & 15, quad = lane >> 4;
    const int colg = blockIdx.x % 48;
    const int rowblk = blockIdx.x / 48;         // 0..63
    const int rowg = rowblk * 4 + wave;         // 0..255

    const uint16_t* ap = H1 + (size_t)(rowg * 16 + l16) * 64 + quad * 8;
    const uint16_t* bp = WT + ((size_t)colg * 64 + l16) * 64 + quad * 8;

    const int which = colg >> 4;   // 0=q 1=k 2=v (block-uniform)
    const int h = colg & 15;
    const int b = rowblk >> 5;                  // batch
    const int tt = rowblk & 31;                 // 64-n tile within batch
    const int bh = b * 16 + h;

    f32x4 acc[4];
#pragma unroll
    for (int c = 0; c < 4; ++c) acc[c] = (f32x4){0.f, 0.f, 0.f, 0.f};

    if (which < 2) {
        // rows = n (16 per wave), cols = d
#pragma unroll
        for (int i = 0; i < 2; ++i) {
            short8 a = ld8(ap + i * 32);
#pragma unroll
            for (int c = 0; c < 4; ++c) {
                acc[c] = MFMA16(a, ld8(bp + (size_t)c * 1024 + i * 32), acc[c]);
            }
        }
        const float sc = (which == 0) ? QSCALE : 1.0f;
#pragma unroll
        for (int c = 0; c < 4; ++c) {
#pragma unroll
            for (int r = 0; r < 4; ++r) {
                tl[(wave * 16 + quad * 4 + r) * 72 + c * 16 + l16] = f2b(acc[c][r] * sc);
            }
        }
        __syncthreads();
        if (which == 0) {
            // n-major store, 32B/thread, full 128B lines
            const int nl = tid >> 2, d0 = (tid & 3) * 16;
            const int n = rowblk * 64 + nl;
            uint16_t* dst = Qb + ((size_t)bh * 2048 + (n & 2047)) * 64 + d0;
            *reinterpret_cast<short8*>(dst) = ld8(&tl[nl * 72 + d0]);
            *reinterpret_cast<short8*>(dst + 8) = ld8(&tl[nl * 72 + d0 + 8]);
        } else {
            // fragment-order store, TWO short8s/thread (offsets tid*8, +2048)
            const int kc = tid >> 7, h2 = (tid >> 6) & 1;
            const int qd = (tid >> 4) & 3, lk = tid & 15;
            const int key = kc * 16 + lk;       // block-local n (first half)
            const int d0 = h2 * 32 + qd * 8;
            uint16_t* dst = Kf + ((size_t)bh * 32 + tt) * 4096 + (size_t)tid * 8;
            *reinterpret_cast<short8*>(dst) = ld8(&tl[key * 72 + d0]);
            // offset 2048 + tid*8 decomposes to kc+2 -> key+32
            *reinterpret_cast<short8*>(dst + 2048) = ld8(&tl[(key + 32) * 72 + d0]);
        }
    } else {
        // V: operand-swapped -> C rows = d, cols = n-local (wave*16 + l16)
#pragma unroll
        for (int i = 0; i < 2; ++i) {
            short8 a = ld8(ap + i * 32);
#pragma unroll
            for (int c = 0; c < 4; ++c) {
                acc[c] = MFMA16(ld8(bp + (size_t)c * 1024 + i * 32), a, acc[c]);
            }
        }
#pragma unroll
        for (int c = 0; c < 4; ++c) {
#pragma unroll
            for (int r = 0; r < 4; ++r) {
                tl[(c * 16 + quad * 4 + r) * 72 + wave * 16 + l16] = f2h(acc[c][r]);
            }
        }
        __syncthreads();
        // paired-kc fragment-order store, TWO short8s/thread
        const int dc = tid >> 7, kp = (tid >> 6) & 1;
        const int qk = (tid >> 4) & 3, ld16 = tid & 15;
        const int d = dc * 16 + ld16;
        const int k0 = kp * 32 + qk * 4;
        uint16_t* dst = Vf + ((size_t)bh * 32 + tt) * 4096 + (size_t)tid * 8;
        union { short8 s; uint64_t u[2]; } pk;
        pk.u[0] = *reinterpret_cast<const uint64_t*>(&tl[d * 72 + k0]);
        pk.u[1] = *reinterpret_cast<const uint64_t*>(&tl[d * 72 + k0 + 16]);
        *reinterpret_cast<short8*>(dst) = pk.s;
        // offset 2048 + tid*8 decomposes to dc+2 -> d+32
        pk.u[0] = *reinterpret_cast<const uint64_t*>(&tl[(d + 32) * 72 + k0]);
        pk.u[1] = *reinterpret_cast<const uint64_t*>(&tl[(d + 32) * 72 + k0 + 16]);
        *reinterpret_cast<short8*>(dst + 2048) = pk.s;
    }
}

// ---------------------------------------------------------------------------
// Flash attention v5: staged LDS, fragment-ordered tiles (zero conflicts),
// G=2 q-reuse (32 q/wave, 128 q/block). S^T trick -> P^T in registers ->
// f16 PV (no P round-trip). No-max exp2 softmax, lane-partial l.
// grid = bh(32) * qchunk(16) = 512 x 256. LDS 34 KB.
// ---------------------------------------------------------------------------
__global__ __launch_bounds__(256) void attn_kernel(const uint16_t* __restrict__ Qb,
                                                   const uint16_t* __restrict__ Kf,
                                                   const uint16_t* __restrict__ Vf,
                                                   uint16_t* __restrict__ AO) {
    __shared__ __align__(16) uint16_t kt[4096];      // K tile, fragment order
    __shared__ __align__(16) uint16_t vt[4096];      // V^T tile, paired fragment order
    __shared__ __align__(16) uint16_t pws[128 * 72]; // epilogue transpose

    const int tid = threadIdx.x;
    const int wave = tid >> 6;
    const int lane = tid & 63;
    const int l16 = lane & 15, quad = lane >> 4;
    const int bh = blockIdx.x >> 4;
    const int qc = blockIdx.x & 15;
    const int qbase = qc * 128 + wave * 32;

    short8 qf[2][2];
#pragma unroll
    for (int g = 0; g < 2; ++g) {
        const uint16_t* qp = Qb + ((size_t)bh * 2048 + qbase + g * 16 + l16) * 64 + quad * 8;
        qf[g][0] = ld8(qp);
        qf[g][1] = ld8(qp + 32);
    }

    f32x4 ot[2][4];
    float lp[2] = {0.f, 0.f};
#pragma unroll
    for (int g = 0; g < 2; ++g)
#pragma unroll
        for (int dc = 0; dc < 4; ++dc) ot[g][dc] = (f32x4){0.f, 0.f, 0.f, 0.f};

    for (int t = 0; t < 32; ++t) {
        __syncthreads();
        {
            const uint16_t* kg = Kf + ((size_t)bh * 32 + t) * 4096 + tid * 8;
            *reinterpret_cast<short8*>(&kt[tid * 8]) = ld8(kg);
            *reinterpret_cast<short8*>(&kt[2048 + tid * 8]) = ld8(kg + 2048);
            const uint16_t* vg = Vf + ((size_t)bh * 32 + t) * 4096 + tid * 8;
            *reinterpret_cast<short8*>(&vt[tid * 8]) = ld8(vg);
            *reinterpret_cast<short8*>(&vt[2048 + tid * 8]) = ld8(vg + 2048);
        }
        __syncthreads();

        // S^T = K . Q^T per 16-key chunk; P^T = exp2(S^T) packed to f16 B-frags
        half4 pb[2][4];
#pragma unroll
        for (int kc = 0; kc < 4; ++kc) {
            const short8 a0 = ld8(&kt[kc * 1024 + lane * 8]);
            const short8 a1 = ld8(&kt[kc * 1024 + 512 + lane * 8]);
#pragma unroll
            for (int g = 0; g < 2; ++g) {
                f32x4 st = {0.f, 0.f, 0.f, 0.f};
                st = MFMA16(a0, qf[g][0], st);
                st = MFMA16(a1, qf[g][1], st);
                float p0 = fexp2(st[0]), p1 = fexp2(st[1]);
                float p2 = fexp2(st[2]), p3 = fexp2(st[3]);
                lp[g] += (p0 + p1) + (p2 + p3);
                half2v lo = __builtin_amdgcn_cvt_pkrtz(p0, p1);
                half2v hi = __builtin_amdgcn_cvt_pkrtz(p2, p3);
                pb[g][kc] = __builtin_shufflevector(lo, hi, 0, 1, 2, 3);
            }
        }

        // O^T += V^T . P^T  (one b128 feeds two kc fragments)
#pragma unroll
        for (int dc = 0; dc < 4; ++dc) {
#pragma unroll
            for (int kp = 0; kp < 2; ++kp) {
                union { short8 s; half4 h[2]; } vv;
                vv.s = ld8(&vt[dc * 1024 + kp * 512 + lane * 8]);
#pragma unroll
                for (int g = 0; g < 2; ++g) {
                    ot[g][dc] = MFMA16F(vv.h[0], pb[g][kp * 2], ot[g][dc]);
                    ot[g][dc] = MFMA16F(vv.h[1], pb[g][kp * 2 + 1], ot[g][dc]);
                }
            }
        }
    }

    // epilogue: l across quads; O^T -> O (block-level LDS transpose)
#pragma unroll
    for (int g = 0; g < 2; ++g) {
        float ls = lp[g];
        ls += __shfl_xor(ls, 16, 64);
        ls += __shfl_xor(ls, 32, 64);
        const float inv = 1.0f / ls;
        uint16_t* pw = &pws[(wave * 32 + g * 16 + l16) * 72];
#pragma unroll
        for (int dc = 0; dc < 4; ++dc) {
            uint32_t* w = reinterpret_cast<uint32_t*>(&pw[dc * 16 + quad * 4]);
            w[0] = pkbf(ot[g][dc][0] * inv, ot[g][dc][1] * inv);
            w[1] = pkbf(ot[g][dc][2] * inv, ot[g][dc][3] * inv);
        }
    }
    __syncthreads();

    // store 128 q rows x 64 d, 64B/thread, coalesced
    const int b = bh >> 4, h = bh & 15;
    const int ql = tid >> 1, d0 = (tid & 1) * 32;
    const int grow = b * 2048 + qc * 128 + ql;
    uint16_t* dst = AO + (size_t)grow * 1024 + h * 64 + d0;
    const uint16_t* src = &pws[ql * 72 + d0];
    *reinterpret_cast<short8*>(dst) = ld8(src);
    *reinterpret_cast<short8*>(dst + 8) = ld8(src + 8);
    *reinterpret_cast<short8*>(dst + 16) = ld8(src + 16);
    *reinterpret_cast<short8*>(dst + 24) = ld8(src + 24);
}

// ---------------------------------------------------------------------------
// proj_fused: out = gelu(AO @ wpa + bpa) @ wpb + bpb. grid 256 x 512.
// ---------------------------------------------------------------------------
__global__ __launch_bounds__(512) void proj_fused(const uint16_t* __restrict__ AO,
                                                  const uint16_t* __restrict__ wpaT,
                                                  const float* __restrict__ bpa,
                                                  const uint16_t* __restrict__ wpbT,
                                                  const float* __restrict__ bpb,
                                                  float* __restrict__ out) {
    __shared__ float ps[4][16][17];
    __shared__ __align__(16) uint16_t h2L[16 * 72];
    const int tid = threadIdx.x;
    const int wave = tid >> 6, lane = tid & 63;
    const int l16 = lane & 15, quad = lane >> 4;
    const int cc = wave & 3, kh = wave >> 2;
    const int rowg = blockIdx.x;

    {
        const uint16_t* ap = AO + (size_t)(rowg * 16 + l16) * 1024 + kh * 512 + quad * 8;
        const uint16_t* bp = wpaT + (size_t)(cc * 16 + l16) * 1024 + kh * 512 + quad * 8;
        f32x4 acc = {0.f, 0.f, 0.f, 0.f};
#pragma unroll 8
        for (int k = 0; k < 16; ++k) {
            acc = MFMA16(ld8(ap + k * 32), ld8(bp + k * 32), acc);
        }
        if (kh == 1) {
#pragma unroll
            for (int r = 0; r < 4; ++r) ps[cc][quad * 4 + r][l16] = acc[r];
        }
        __syncthreads();
        if (kh == 0) {
            const int col = cc * 16 + l16;
            const float bv = bpa[col];
#pragma unroll
            for (int r = 0; r < 4; ++r) {
                float v = acc[r] + ps[cc][quad * 4 + r][l16] + bv;
                h2L[(quad * 4 + r) * 72 + col] = f2b(gelu_exact(v));
            }
        }
        __syncthreads();
    }

    const short8 a0 = ld8(&h2L[l16 * 72 + quad * 8]);
    const short8 a1 = ld8(&h2L[l16 * 72 + 32 + quad * 8]);
#pragma unroll
    for (int i = 0; i < 8; ++i) {
        const int col0 = (wave * 8 + i) * 16;
        const uint16_t* bp = wpbT + (size_t)(col0 + l16) * 64 + quad * 8;
        f32x4 acc = {0.f, 0.f, 0.f, 0.f};
        acc = MFMA16(a0, ld8(bp), acc);
        acc = MFMA16(a1, ld8(bp + 32), acc);
        const float bv = bpb[col0 + l16];
#pragma unroll
        for (int r = 0; r < 4; ++r) {
            int row = rowg * 16 + quad * 4 + r;
            out[(size_t)row * 1024 + col0 + l16] = acc[r] + bv;
        }
    }
}

// ---------------------------------------------------------------------------
extern "C" void kernel_launch(void* const* d_in, const int* in_sizes, int n_in,
                              void* d_out, int out_size, void* d_ws, size_t ws_size,
                              hipStream_t stream) {
    const float* x   = (const float*)d_in[0];
    const float* wqa = (const float*)d_in[1];
    const float* wqb = (const float*)d_in[2];
    const float* wpa = (const float*)d_in[3];
    const float* bpa = (const float*)d_in[4];
    const float* wpb = (const float*)d_in[5];
    const float* bpb = (const float*)d_in[6];
    float* out = (float*)d_out;
    uint16_t* ws = (uint16_t*)d_ws;

    uint16_t* wqaT = ws + 0;         //  64x1024
    uint16_t* wqbT = ws + 65536;     // 3072x64
    uint16_t* wpaT = ws + 262144;    //  64x1024
    uint16_t* wpbT = ws + 327680;    // 1024x64
    uint16_t* h1   = ws + 393216;    // 4096x64
    uint16_t* Qb   = ws + 655360;    // [32][2048][64] bf16
    uint16_t* Kf   = ws + 4849664;   // [32][32][4096] bf16, fragment order
    uint16_t* xb   = Kf;             // x bf16 — dead before Kf written
    uint16_t* Vf   = ws + 9043968;   // [32][32][4096] f16, paired fragment order
    uint16_t* AO   = ws + 13238272;  // 4096x1024 bf16
    (void)in_sizes; (void)n_in; (void)out_size; (void)ws_size;

    prep<<<3584, 256, 0, stream>>>(x, wqa, wqb, wpa, wpb, xb, wqaT, wqbT, wpaT, wpbT);
    rank_gemm<<<256, 512, 0, stream>>>(xb, wqaT, h1);
    expand_qkv<<<3072, 256, 0, stream>>>(h1, wqbT, Qb, Kf, Vf);
    attn_kernel<<<512, 256, 0, stream>>>(Qb, Kf, Vf, AO);
    proj_fused<<<256, 512, 0, stream>>>(AO, wpaT, bpa, wpbT, bpb, out);
}